// Round 1
// baseline (622.460 us; speedup 1.0000x reference)
//
#include <hip/hip_runtime.h>
#include <stdint.h>

typedef float f32x4 __attribute__((ext_vector_type(4)));
typedef short s16x8 __attribute__((ext_vector_type(8)));
typedef unsigned short u16x4 __attribute__((ext_vector_type(4)));

#define SCALE_F 0.08838834764831845f

__device__ __forceinline__ unsigned short f32_to_bf16(float f) {
    union { float f; unsigned int u; } v; v.f = f;
    return (unsigned short)((v.u + 0x7FFFu + ((v.u >> 16) & 1u)) >> 16);
}

__device__ __forceinline__ void gload16(const void* g, void* l) {
    __builtin_amdgcn_global_load_lds((const __attribute__((address_space(1))) unsigned int*)g,
                                     (__attribute__((address_space(3))) unsigned int*)l,
                                     16, 0, 0);
}

// ---------------- fp32 -> bf16 elementwise ----------------
__global__ void k_conv_bf16(const float* __restrict__ in, unsigned short* __restrict__ out, int n4) {
    int i = blockIdx.x * 256 + threadIdx.x;
    if (i >= n4) return;
    f32x4 v = ((const f32x4*)in)[i];
    u16x4 o;
    o[0] = f32_to_bf16(v[0]); o[1] = f32_to_bf16(v[1]);
    o[2] = f32_to_bf16(v[2]); o[3] = f32_to_bf16(v[3]);
    ((u16x4*)out)[i] = o;
}

// ---------------- fp32 [R][C] -> bf16 [C][R] transpose ----------------
__global__ void k_transpose_bf16(const float* __restrict__ in, unsigned short* __restrict__ out,
                                 int R, int C) {
    __shared__ float tile[64][65];
    const int rb = blockIdx.y * 64, cb = blockIdx.x * 64;
    const int t = threadIdx.x;
    const int lr = t >> 4, lc4 = (t & 15) * 4;
#pragma unroll
    for (int i = 0; i < 4; ++i) {
        int r = i * 16 + lr;
        f32x4 v = *(const f32x4*)(in + (size_t)(rb + r) * C + cb + lc4);
        tile[r][lc4 + 0] = v[0]; tile[r][lc4 + 1] = v[1];
        tile[r][lc4 + 2] = v[2]; tile[r][lc4 + 3] = v[3];
    }
    __syncthreads();
#pragma unroll
    for (int i = 0; i < 4; ++i) {
        int oc = cb + i * 16 + lr;
        u16x4 o;
#pragma unroll
        for (int j = 0; j < 4; ++j)
            o[j] = f32_to_bf16(tile[lc4 + j][i * 16 + lr]);
        *(u16x4*)(out + (size_t)oc * R + rb + lc4) = o;
    }
}

// ---------------- bf16 GEMM: C[M][N] = A[M][K] * Bt[N][K]^T (fp32 out) ----------------
__global__ __launch_bounds__(256, 2)
void k_gemm_bt(const unsigned short* __restrict__ A, const unsigned short* __restrict__ Bt,
               float* __restrict__ C, int N, int K) {
    __shared__ __align__(16) unsigned short As[4096];  // [kc 4][row 128][8]
    __shared__ __align__(16) unsigned short Bs[4096];  // [kc 4][col 128][8]
    const int tid = threadIdx.x;
    const int lane = tid & 63, wid = tid >> 6;
    const int g = lane >> 4, l15 = lane & 15;
    const int nwg = gridDim.x;
    const int bid = blockIdx.x;
    const int swz = (bid & 7) * (nwg >> 3) + (bid >> 3);   // bijective: nwg % 8 == 0
    const int ntn = N >> 7;
    const int bm = swz / ntn, bn = swz - bm * ntn;
    const int brow = bm << 7, bcol = bn << 7;
    const int wr = (wid >> 1) << 6, wc = (wid & 1) << 6;

    const unsigned short* gA = A + (size_t)(brow + (tid & 127)) * K + (tid >> 7) * 8;
    const unsigned short* gB = Bt + (size_t)(bcol + (tid & 127)) * K + (tid >> 7) * 8;
    unsigned short* lA = As + tid * 8;
    unsigned short* lB = Bs + tid * 8;

    f32x4 acc[4][4] = {};
    for (int kt = 0; kt < K; kt += 32) {
        gload16(gA + kt,      lA);
        gload16(gA + kt + 16, lA + 2048);
        gload16(gB + kt,      lB);
        gload16(gB + kt + 16, lB + 2048);
        __syncthreads();
        s16x8 af[4], bfr[4];
#pragma unroll
        for (int i = 0; i < 4; ++i)
            af[i] = *(const s16x8*)(As + (g * 128 + wr + i * 16 + l15) * 8);
#pragma unroll
        for (int j = 0; j < 4; ++j)
            bfr[j] = *(const s16x8*)(Bs + (g * 128 + wc + j * 16 + l15) * 8);
#pragma unroll
        for (int i = 0; i < 4; ++i)
#pragma unroll
            for (int j = 0; j < 4; ++j)
                acc[i][j] = __builtin_amdgcn_mfma_f32_16x16x32_bf16(af[i], bfr[j], acc[i][j], 0, 0, 0);
        __syncthreads();
    }
#pragma unroll
    for (int i = 0; i < 4; ++i)
#pragma unroll
        for (int j = 0; j < 4; ++j)
#pragma unroll
            for (int r = 0; r < 4; ++r)
                C[(size_t)(brow + wr + i * 16 + g * 4 + r) * N + bcol + wc + j * 16 + l15] = acc[i][j][r];
}

// ---------------- RoPE + pack Q/K, transpose V ----------------
__global__ void k_rope_pack(const float* __restrict__ qkv, const float* __restrict__ cosT,
                            const float* __restrict__ sinT, unsigned short* __restrict__ Qb,
                            unsigned short* __restrict__ Kb, unsigned short* __restrict__ Vt) {
    const int col = blockIdx.x * 256 + threadIdx.x;  // 0..6143
    const int t = blockIdx.y;
    const float v = qkv[(size_t)t * 6144 + col];
    const int d = col & 127;
    if (col < 5120) {
        float o = v;
        if (d < 64) {
            float c = cosT[t * 64 + d], s = sinT[t * 64 + d];
            float partner = qkv[(size_t)t * 6144 + ((d < 32) ? col + 32 : col - 32)];
            o = (d < 32) ? (v * c - partner * s) : (v * c + partner * s);
        }
        unsigned short ob = f32_to_bf16(o);
        if (col < 4096) {
            int h = col >> 7;
            Qb[((size_t)h * 2048 + t) * 128 + d] = ob;
        } else {
            int hk = (col - 4096) >> 7;
            Kb[((size_t)hk * 2048 + t) * 128 + d] = ob;
        }
    } else {
        int hk = (col - 5120) >> 7;
        Vt[((size_t)hk * 128 + d) * 2048 + t] = f32_to_bf16(v);
    }
}

// ---------------- causal GQA flash attention ----------------
// Q [32][2048][128], K [8][2048][128], Vt [8][128][2048] -> O bf16 [2048][4096]
__global__ __launch_bounds__(256, 2)
void k_attn(const unsigned short* __restrict__ Qb, const unsigned short* __restrict__ Kb,
            const unsigned short* __restrict__ Vt, unsigned short* __restrict__ Ob) {
    __shared__ __align__(16) unsigned short Ks[4096];   // [dc 16][key 32][8]
    __shared__ __align__(16) unsigned short Vs[4096];   // [kc 4][d 128][8]
    __shared__ __align__(16) unsigned short Pl[4][512]; // per-wave [kc 4][row 16][8]
    const int h = blockIdx.y, hk = h >> 2;
    const int qb0 = blockIdx.x << 6;
    const int tid = threadIdx.x, lane = tid & 63, wid = tid >> 6;
    const int g = lane >> 4, l15 = lane & 15;
    const int qrow = qb0 + wid * 16;

    s16x8 aq[4];
#pragma unroll
    for (int kc = 0; kc < 4; ++kc)
        aq[kc] = *(const s16x8*)(Qb + ((size_t)h * 2048 + qrow + l15) * 128 + kc * 32 + g * 8);

    const unsigned short* gK = Kb + ((size_t)hk * 2048 + (tid & 31)) * 128 + (tid >> 5) * 8;
    const unsigned short* gV = Vt + ((size_t)hk * 128 + (tid & 127)) * 2048 + (tid >> 7) * 8;
    unsigned short* lK = Ks + tid * 8;
    unsigned short* lV = Vs + tid * 8;

    f32x4 oacc[8] = {};
    float m[4] = {-1e30f, -1e30f, -1e30f, -1e30f};
    float l[4] = {0.f, 0.f, 0.f, 0.f};
    const int nkb = (qb0 >> 5) + 2;
    for (int kb = 0; kb < nkb; ++kb) {
        const int k0 = kb << 5;
        gload16(gK + (size_t)kb * 4096,      lK);
        gload16(gK + (size_t)kb * 4096 + 64, lK + 2048);
        gload16(gV + k0,      lV);
        gload16(gV + k0 + 16, lV + 2048);
        __syncthreads();
        f32x4 s0 = {}, s1 = {};
#pragma unroll
        for (int kc = 0; kc < 4; ++kc) {
            s16x8 b0 = *(const s16x8*)(Ks + ((kc * 4 + g) * 32 + l15) * 8);
            s16x8 b1 = *(const s16x8*)(Ks + ((kc * 4 + g) * 32 + 16 + l15) * 8);
            s0 = __builtin_amdgcn_mfma_f32_16x16x32_bf16(aq[kc], b0, s0, 0, 0, 0);
            s1 = __builtin_amdgcn_mfma_f32_16x16x32_bf16(aq[kc], b1, s1, 0, 0, 0);
        }
        float scal[4];
#pragma unroll
        for (int r = 0; r < 4; ++r) {
            const int q_idx = qrow + g * 4 + r;
            float x0 = s0[r] * SCALE_F;
            float x1 = s1[r] * SCALE_F;
            if (k0 + l15 > q_idx)      x0 = -3e38f;
            if (k0 + 16 + l15 > q_idx) x1 = -3e38f;
            float mx = fmaxf(x0, x1);
            mx = fmaxf(mx, __shfl_xor(mx, 1, 16));
            mx = fmaxf(mx, __shfl_xor(mx, 2, 16));
            mx = fmaxf(mx, __shfl_xor(mx, 4, 16));
            mx = fmaxf(mx, __shfl_xor(mx, 8, 16));
            float mnew = fmaxf(m[r], mx);
            scal[r] = __expf(m[r] - mnew);
            m[r] = mnew;
            float p0 = __expf(x0 - mnew);
            float p1 = __expf(x1 - mnew);
            s0[r] = p0; s1[r] = p1;
            float ps = p0 + p1;
            ps += __shfl_xor(ps, 1, 16);
            ps += __shfl_xor(ps, 2, 16);
            ps += __shfl_xor(ps, 4, 16);
            ps += __shfl_xor(ps, 8, 16);
            l[r] = l[r] * scal[r] + ps;
        }
#pragma unroll
        for (int j = 0; j < 8; ++j) {
            oacc[j][0] *= scal[0]; oacc[j][1] *= scal[1];
            oacc[j][2] *= scal[2]; oacc[j][3] *= scal[3];
        }
#pragma unroll
        for (int r = 0; r < 4; ++r) {
            const int row = g * 4 + r;
            Pl[wid][((l15 >> 3) * 16 + row) * 8 + (l15 & 7)]        = f32_to_bf16(s0[r]);
            Pl[wid][(((16 + l15) >> 3) * 16 + row) * 8 + (l15 & 7)] = f32_to_bf16(s1[r]);
        }
        s16x8 ap = *(const s16x8*)(&Pl[wid][(g * 16 + l15) * 8]);
#pragma unroll
        for (int j = 0; j < 8; ++j) {
            s16x8 bv = *(const s16x8*)(Vs + (g * 128 + j * 16 + l15) * 8);
            oacc[j] = __builtin_amdgcn_mfma_f32_16x16x32_bf16(ap, bv, oacc[j], 0, 0, 0);
        }
        __syncthreads();
    }
#pragma unroll
    for (int j = 0; j < 8; ++j)
#pragma unroll
        for (int r = 0; r < 4; ++r) {
            const int q_idx = qrow + g * 4 + r;
            Ob[(size_t)q_idx * 4096 + h * 128 + j * 16 + l15] = f32_to_bf16(oacc[j][r] / l[r]);
        }
}

extern "C" void kernel_launch(void* const* d_in, const int* in_sizes, int n_in,
                              void* d_out, int out_size, void* d_ws, size_t ws_size,
                              hipStream_t stream) {
    const float* x     = (const float*)d_in[0];
    // d_in[1] (attention_mask) unused: causal mask applied analytically
    const float* cosT  = (const float*)d_in[2];
    const float* sinT  = (const float*)d_in[3];
    const float* w_qkv = (const float*)d_in[4];
    const float* w_o   = (const float*)d_in[5];
    float* out = (float*)d_out;

    char* ws = (char*)d_ws;
    unsigned short* wT  = (unsigned short*)(ws + 0);           // 50.3 MB (w_qkv^T, later w_o^T)
    float*          qkv = (float*)(ws + 50331648);             // 50.3 MB fp32
    unsigned short* Ob  = (unsigned short*)(ws + 50331648);    // reuse qkv region after rope
    unsigned short* xb  = (unsigned short*)(ws + 100663296);   // 16.8 MB
    unsigned short* Qb  = xb;                                  // reuse after gemm1
    unsigned short* Kb  = (unsigned short*)(ws + 117440512);   // 4.2 MB
    unsigned short* Vt  = (unsigned short*)(ws + 121634816);   // 4.2 MB

    k_conv_bf16<<<8192, 256, 0, stream>>>(x, xb, 2097152);
    k_transpose_bf16<<<dim3(96, 64), 256, 0, stream>>>(w_qkv, wT, 4096, 6144);
    k_gemm_bt<<<768, 256, 0, stream>>>(xb, wT, qkv, 6144, 4096);          // qkv = x @ w_qkv
    k_rope_pack<<<dim3(24, 2048), 256, 0, stream>>>(qkv, cosT, sinT, Qb, Kb, Vt);
    k_transpose_bf16<<<dim3(64, 64), 256, 0, stream>>>(w_o, wT, 4096, 4096);
    k_attn<<<dim3(32, 32), 256, 0, stream>>>(Qb, Kb, Vt, Ob);
    k_gemm_bt<<<512, 256, 0, stream>>>(Ob, wT, out, 4096, 4096);          // out = O @ w_o
}

// Round 2
// 538.213 us; speedup vs baseline: 1.1565x; 1.1565x over previous
//
#include <hip/hip_runtime.h>
#include <stdint.h>

typedef float f32x4 __attribute__((ext_vector_type(4)));
typedef short s16x8 __attribute__((ext_vector_type(8)));
typedef unsigned short u16x4 __attribute__((ext_vector_type(4)));

#define SCALE_F 0.08838834764831845f

__device__ __forceinline__ unsigned short f32_to_bf16(float f) {
    union { float f; unsigned int u; } v; v.f = f;
    return (unsigned short)((v.u + 0x7FFFu + ((v.u >> 16) & 1u)) >> 16);
}

__device__ __forceinline__ void gload16(const void* g, void* l) {
    __builtin_amdgcn_global_load_lds((const __attribute__((address_space(1))) unsigned int*)g,
                                     (__attribute__((address_space(3))) unsigned int*)l,
                                     16, 0, 0);
}

// ---------------- fp32 -> bf16 elementwise ----------------
__global__ void k_conv_bf16(const float* __restrict__ in, unsigned short* __restrict__ out, int n4) {
    int i = blockIdx.x * 256 + threadIdx.x;
    if (i >= n4) return;
    f32x4 v = ((const f32x4*)in)[i];
    u16x4 o;
    o[0] = f32_to_bf16(v[0]); o[1] = f32_to_bf16(v[1]);
    o[2] = f32_to_bf16(v[2]); o[3] = f32_to_bf16(v[3]);
    ((u16x4*)out)[i] = o;
}

// ---------------- fp32 [R][C] -> bf16 [C][R] transpose ----------------
__global__ void k_transpose_bf16(const float* __restrict__ in, unsigned short* __restrict__ out,
                                 int R, int C) {
    __shared__ float tile[64][65];
    const int rb = blockIdx.y * 64, cb = blockIdx.x * 64;
    const int t = threadIdx.x;
    const int lr = t >> 4, lc4 = (t & 15) * 4;
#pragma unroll
    for (int i = 0; i < 4; ++i) {
        int r = i * 16 + lr;
        f32x4 v = *(const f32x4*)(in + (size_t)(rb + r) * C + cb + lc4);
        tile[r][lc4 + 0] = v[0]; tile[r][lc4 + 1] = v[1];
        tile[r][lc4 + 2] = v[2]; tile[r][lc4 + 3] = v[3];
    }
    __syncthreads();
#pragma unroll
    for (int i = 0; i < 4; ++i) {
        int oc = cb + i * 16 + lr;
        u16x4 o;
#pragma unroll
        for (int j = 0; j < 4; ++j)
            o[j] = f32_to_bf16(tile[lc4 + j][i * 16 + lr]);
        *(u16x4*)(out + (size_t)oc * R + rb + lc4) = o;
    }
}

// ---------------- pipelined bf16 GEMM: C[M][N] = A[M][K] * Bt[N][K]^T ----------------
// BM=256, BK=32, ring-4 LDS buffers, prefetch distance 3, counted vmcnt.
// LDS layout per buffer: [grp 16][kc 4][r 16][8] shorts -> element (grp*16+r, kc*8+j).
// 512 threads = 8 waves (2 M x 4 N); per-wave output 128 x (BN/4).
template<int BN>
__global__ __launch_bounds__(512, 1)
void k_gemm256(const unsigned short* __restrict__ A, const unsigned short* __restrict__ Bt,
               float* __restrict__ C, int N, int K) {
    constexpr int ASZ = 8192;            // shorts per A buffer (256x32)
    constexpr int BSZ = BN * 32;         // shorts per B buffer
    constexpr int NFRAG = BN / 64;       // B frags per wave
    __shared__ __align__(16) unsigned short As[4 * ASZ];
    __shared__ __align__(16) unsigned short Bs[4 * BSZ];
    const int tid = threadIdx.x;
    const int lane = tid & 63, wid = tid >> 6;
    const int g = lane >> 4, l15 = lane & 15;
    const int wave_m = wid >> 2, wave_n = wid & 3;
    const int nwg = gridDim.x, bid = blockIdx.x;
    const int swz = (bid & 7) * (nwg >> 3) + (bid >> 3);   // bijective: nwg % 8 == 0
    const int ntn = N / BN;
    const int bm = swz / ntn, bn = swz - bm * ntn;
    const int brow = bm << 8, bcol = bn * BN;

    // staging: thread -> chunk c = i*512 + tid; grp=c>>6, kc=(c>>4)&3, r=c&15
    const int rowS = ((tid >> 6) << 4) | (tid & 15);
    const int kcS = (tid >> 4) & 3;
    const unsigned short* sA = A + (size_t)(brow + rowS) * K + kcS * 8;
    const unsigned short* sB = Bt + (size_t)(bcol + rowS) * K + kcS * 8;

    // fragment read base offsets (shorts)
    const int aoff = (wave_m * 8 * 64 + g * 16 + l15) * 8;
    const int boff = (wave_n * NFRAG * 64 + g * 16 + l15) * 8;

    f32x4 acc[8][NFRAG] = {};
    const int nt = K >> 5;

    auto stageA = [&](int t) {
        unsigned short* d = As + (t & 3) * ASZ + tid * 8;
        const unsigned short* s = sA + (size_t)t * 32;
        gload16(s, d);
        gload16(s + (size_t)128 * K, d + 4096);
    };
    auto stageB = [&](int t) {
        unsigned short* d = Bs + (t & 3) * BSZ + tid * 8;
        const unsigned short* s = sB + (size_t)t * 32;
        gload16(s, d);
        if constexpr (BN == 256) gload16(s + (size_t)128 * K, d + 4096);
    };

    stageA(0); stageB(0); stageA(1); stageB(1); stageA(2); stageB(2);
    if constexpr (BN == 256) asm volatile("s_waitcnt vmcnt(8)" ::: "memory");
    else                     asm volatile("s_waitcnt vmcnt(6)" ::: "memory");
    __builtin_amdgcn_s_barrier();

    for (int t = 0; t < nt; ++t) {
        const int ba = (t & 3) * ASZ, bb = (t & 3) * BSZ;
        s16x8 af[4], bf[NFRAG];
        // ---- phase A: A-frags 0-3 + all B-frags; prefetch A of t+3 ----
#pragma unroll
        for (int f = 0; f < 4; ++f) af[f] = *(const s16x8*)(As + ba + aoff + f * 512);
#pragma unroll
        for (int j = 0; j < NFRAG; ++j) bf[j] = *(const s16x8*)(Bs + bb + boff + j * 512);
        if (t + 3 < nt) stageA(t + 3);
        __builtin_amdgcn_s_barrier();
        __builtin_amdgcn_s_setprio(1);
#pragma unroll
        for (int f = 0; f < 4; ++f)
#pragma unroll
            for (int j = 0; j < NFRAG; ++j)
                acc[f][j] = __builtin_amdgcn_mfma_f32_16x16x32_bf16(af[f], bf[j], acc[f][j], 0, 0, 0);
        __builtin_amdgcn_s_setprio(0);
        __builtin_amdgcn_s_barrier();
        // ---- phase B: A-frags 4-7; prefetch B of t+3; counted vmcnt ----
#pragma unroll
        for (int f = 0; f < 4; ++f) af[f] = *(const s16x8*)(As + ba + aoff + (4 + f) * 512);
        if (t + 3 < nt) stageB(t + 3);
        if (t + 3 < nt) {
            if constexpr (BN == 256) asm volatile("s_waitcnt vmcnt(8)" ::: "memory");
            else                     asm volatile("s_waitcnt vmcnt(6)" ::: "memory");
        } else if (t + 2 < nt) {
            if constexpr (BN == 256) asm volatile("s_waitcnt vmcnt(4)" ::: "memory");
            else                     asm volatile("s_waitcnt vmcnt(3)" ::: "memory");
        } else if (t + 1 < nt) {
            asm volatile("s_waitcnt vmcnt(0)" ::: "memory");
        }
        __builtin_amdgcn_s_barrier();
        __builtin_amdgcn_s_setprio(1);
#pragma unroll
        for (int f = 0; f < 4; ++f)
#pragma unroll
            for (int j = 0; j < NFRAG; ++j)
                acc[4 + f][j] = __builtin_amdgcn_mfma_f32_16x16x32_bf16(af[f], bf[j], acc[4 + f][j], 0, 0, 0);
        __builtin_amdgcn_s_setprio(0);
        __builtin_amdgcn_s_barrier();
    }

#pragma unroll
    for (int f = 0; f < 8; ++f)
#pragma unroll
        for (int j = 0; j < NFRAG; ++j)
#pragma unroll
            for (int r = 0; r < 4; ++r)
                C[(size_t)(brow + wave_m * 128 + f * 16 + g * 4 + r) * N
                  + bcol + wave_n * (BN / 4) + j * 16 + l15] = acc[f][j][r];
}

// ---------------- RoPE + pack Q/K, transpose V ----------------
__global__ void k_rope_pack(const float* __restrict__ qkv, const float* __restrict__ cosT,
                            const float* __restrict__ sinT, unsigned short* __restrict__ Qb,
                            unsigned short* __restrict__ Kb, unsigned short* __restrict__ Vt) {
    const int col = blockIdx.x * 256 + threadIdx.x;  // 0..6143
    const int t = blockIdx.y;
    const float v = qkv[(size_t)t * 6144 + col];
    const int d = col & 127;
    if (col < 5120) {
        float o = v;
        if (d < 64) {
            float c = cosT[t * 64 + d], s = sinT[t * 64 + d];
            float partner = qkv[(size_t)t * 6144 + ((d < 32) ? col + 32 : col - 32)];
            o = (d < 32) ? (v * c - partner * s) : (v * c + partner * s);
        }
        unsigned short ob = f32_to_bf16(o);
        if (col < 4096) {
            int h = col >> 7;
            Qb[((size_t)h * 2048 + t) * 128 + d] = ob;
        } else {
            int hk = (col - 4096) >> 7;
            Kb[((size_t)hk * 2048 + t) * 128 + d] = ob;
        }
    } else {
        int hk = (col - 5120) >> 7;
        Vt[((size_t)hk * 128 + d) * 2048 + t] = f32_to_bf16(v);
    }
}

// ---------------- causal GQA flash attention ----------------
__global__ __launch_bounds__(256, 2)
void k_attn(const unsigned short* __restrict__ Qb, const unsigned short* __restrict__ Kb,
            const unsigned short* __restrict__ Vt, unsigned short* __restrict__ Ob) {
    __shared__ __align__(16) unsigned short Ks[4096];   // [dc 16][key 32][8]
    __shared__ __align__(16) unsigned short Vs[4096];   // [kc 4][d 128][8]
    __shared__ __align__(16) unsigned short Pl[4][512]; // per-wave [kc 4][row 16][8]
    const int h = blockIdx.y, hk = h >> 2;
    const int qb0 = blockIdx.x << 6;
    const int tid = threadIdx.x, lane = tid & 63, wid = tid >> 6;
    const int g = lane >> 4, l15 = lane & 15;
    const int qrow = qb0 + wid * 16;

    s16x8 aq[4];
#pragma unroll
    for (int kc = 0; kc < 4; ++kc)
        aq[kc] = *(const s16x8*)(Qb + ((size_t)h * 2048 + qrow + l15) * 128 + kc * 32 + g * 8);

    const unsigned short* gK = Kb + ((size_t)hk * 2048 + (tid & 31)) * 128 + (tid >> 5) * 8;
    const unsigned short* gV = Vt + ((size_t)hk * 128 + (tid & 127)) * 2048 + (tid >> 7) * 8;
    unsigned short* lK = Ks + tid * 8;
    unsigned short* lV = Vs + tid * 8;

    f32x4 oacc[8] = {};
    float m[4] = {-1e30f, -1e30f, -1e30f, -1e30f};
    float l[4] = {0.f, 0.f, 0.f, 0.f};
    const int nkb = (qb0 >> 5) + 2;
    for (int kb = 0; kb < nkb; ++kb) {
        const int k0 = kb << 5;
        gload16(gK + (size_t)kb * 4096,      lK);
        gload16(gK + (size_t)kb * 4096 + 64, lK + 2048);
        gload16(gV + k0,      lV);
        gload16(gV + k0 + 16, lV + 2048);
        __syncthreads();
        f32x4 s0 = {}, s1 = {};
#pragma unroll
        for (int kc = 0; kc < 4; ++kc) {
            s16x8 b0 = *(const s16x8*)(Ks + ((kc * 4 + g) * 32 + l15) * 8);
            s16x8 b1 = *(const s16x8*)(Ks + ((kc * 4 + g) * 32 + 16 + l15) * 8);
            s0 = __builtin_amdgcn_mfma_f32_16x16x32_bf16(aq[kc], b0, s0, 0, 0, 0);
            s1 = __builtin_amdgcn_mfma_f32_16x16x32_bf16(aq[kc], b1, s1, 0, 0, 0);
        }
        float scal[4];
#pragma unroll
        for (int r = 0; r < 4; ++r) {
            const int q_idx = qrow + g * 4 + r;
            float x0 = s0[r] * SCALE_F;
            float x1 = s1[r] * SCALE_F;
            if (k0 + l15 > q_idx)      x0 = -3e38f;
            if (k0 + 16 + l15 > q_idx) x1 = -3e38f;
            float mx = fmaxf(x0, x1);
            mx = fmaxf(mx, __shfl_xor(mx, 1, 16));
            mx = fmaxf(mx, __shfl_xor(mx, 2, 16));
            mx = fmaxf(mx, __shfl_xor(mx, 4, 16));
            mx = fmaxf(mx, __shfl_xor(mx, 8, 16));
            float mnew = fmaxf(m[r], mx);
            scal[r] = __expf(m[r] - mnew);
            m[r] = mnew;
            float p0 = __expf(x0 - mnew);
            float p1 = __expf(x1 - mnew);
            s0[r] = p0; s1[r] = p1;
            float ps = p0 + p1;
            ps += __shfl_xor(ps, 1, 16);
            ps += __shfl_xor(ps, 2, 16);
            ps += __shfl_xor(ps, 4, 16);
            ps += __shfl_xor(ps, 8, 16);
            l[r] = l[r] * scal[r] + ps;
        }
#pragma unroll
        for (int j = 0; j < 8; ++j) {
            oacc[j][0] *= scal[0]; oacc[j][1] *= scal[1];
            oacc[j][2] *= scal[2]; oacc[j][3] *= scal[3];
        }
#pragma unroll
        for (int r = 0; r < 4; ++r) {
            const int row = g * 4 + r;
            Pl[wid][((l15 >> 3) * 16 + row) * 8 + (l15 & 7)]        = f32_to_bf16(s0[r]);
            Pl[wid][(((16 + l15) >> 3) * 16 + row) * 8 + (l15 & 7)] = f32_to_bf16(s1[r]);
        }
        s16x8 ap = *(const s16x8*)(&Pl[wid][(g * 16 + l15) * 8]);
#pragma unroll
        for (int j = 0; j < 8; ++j) {
            s16x8 bv = *(const s16x8*)(Vs + (g * 128 + j * 16 + l15) * 8);
            oacc[j] = __builtin_amdgcn_mfma_f32_16x16x32_bf16(ap, bv, oacc[j], 0, 0, 0);
        }
        __syncthreads();
    }
#pragma unroll
    for (int j = 0; j < 8; ++j)
#pragma unroll
        for (int r = 0; r < 4; ++r) {
            const int q_idx = qrow + g * 4 + r;
            Ob[(size_t)q_idx * 4096 + h * 128 + j * 16 + l15] = f32_to_bf16(oacc[j][r] / l[r]);
        }
}

extern "C" void kernel_launch(void* const* d_in, const int* in_sizes, int n_in,
                              void* d_out, int out_size, void* d_ws, size_t ws_size,
                              hipStream_t stream) {
    const float* x     = (const float*)d_in[0];
    const float* cosT  = (const float*)d_in[2];
    const float* sinT  = (const float*)d_in[3];
    const float* w_qkv = (const float*)d_in[4];
    const float* w_o   = (const float*)d_in[5];
    float* out = (float*)d_out;

    char* ws = (char*)d_ws;
    unsigned short* wT  = (unsigned short*)(ws + 0);           // 50.3 MB (w_qkv^T, later w_o^T)
    float*          qkv = (float*)(ws + 50331648);             // 50.3 MB fp32
    unsigned short* Ob  = (unsigned short*)(ws + 50331648);    // reuse qkv region after rope
    unsigned short* xb  = (unsigned short*)(ws + 100663296);   // 16.8 MB
    unsigned short* Qb  = xb;                                  // reuse after gemm1
    unsigned short* Kb  = (unsigned short*)(ws + 117440512);   // 4.2 MB
    unsigned short* Vt  = (unsigned short*)(ws + 121634816);   // 4.2 MB

    k_conv_bf16<<<8192, 256, 0, stream>>>(x, xb, 2097152);
    k_transpose_bf16<<<dim3(96, 64), 256, 0, stream>>>(w_qkv, wT, 4096, 6144);
    k_gemm256<256><<<192, 512, 0, stream>>>(xb, wT, qkv, 6144, 4096);     // qkv = x @ w_qkv
    k_rope_pack<<<dim3(24, 2048), 256, 0, stream>>>(qkv, cosT, sinT, Qb, Kb, Vt);
    k_transpose_bf16<<<dim3(64, 64), 256, 0, stream>>>(w_o, wT, 4096, 4096);
    k_attn<<<dim3(32, 32), 256, 0, stream>>>(Qb, Kb, Vt, Ob);
    k_gemm256<128><<<256, 512, 0, stream>>>(Ob, wT, out, 4096, 4096);     // out = O @ w_o
}

// Round 3
// 500.365 us; speedup vs baseline: 1.2440x; 1.0756x over previous
//
#include <hip/hip_runtime.h>
#include <stdint.h>

typedef float f32x4 __attribute__((ext_vector_type(4)));
typedef short s16x8 __attribute__((ext_vector_type(8)));
typedef unsigned short u16x4 __attribute__((ext_vector_type(4)));

#define SCALE_F 0.08838834764831845f

__device__ __forceinline__ unsigned short f32_to_bf16(float f) {
    union { float f; unsigned int u; } v; v.f = f;
    return (unsigned short)((v.u + 0x7FFFu + ((v.u >> 16) & 1u)) >> 16);
}

__device__ __forceinline__ void gload16(const void* g, void* l) {
    __builtin_amdgcn_global_load_lds((const __attribute__((address_space(1))) unsigned int*)g,
                                     (__attribute__((address_space(3))) unsigned int*)l,
                                     16, 0, 0);
}

// ---------------- fp32 -> bf16 elementwise ----------------
__global__ void k_conv_bf16(const float* __restrict__ in, unsigned short* __restrict__ out, int n4) {
    int i = blockIdx.x * 256 + threadIdx.x;
    if (i >= n4) return;
    f32x4 v = ((const f32x4*)in)[i];
    u16x4 o;
    o[0] = f32_to_bf16(v[0]); o[1] = f32_to_bf16(v[1]);
    o[2] = f32_to_bf16(v[2]); o[3] = f32_to_bf16(v[3]);
    ((u16x4*)out)[i] = o;
}

// ---------------- fp32 [R][C] -> bf16 [C][R] transpose ----------------
__global__ void k_transpose_bf16(const float* __restrict__ in, unsigned short* __restrict__ out,
                                 int R, int C) {
    __shared__ float tile[64][65];
    const int rb = blockIdx.y * 64, cb = blockIdx.x * 64;
    const int t = threadIdx.x;
    const int lr = t >> 4, lc4 = (t & 15) * 4;
#pragma unroll
    for (int i = 0; i < 4; ++i) {
        int r = i * 16 + lr;
        f32x4 v = *(const f32x4*)(in + (size_t)(rb + r) * C + cb + lc4);
        tile[r][lc4 + 0] = v[0]; tile[r][lc4 + 1] = v[1];
        tile[r][lc4 + 2] = v[2]; tile[r][lc4 + 3] = v[3];
    }
    __syncthreads();
#pragma unroll
    for (int i = 0; i < 4; ++i) {
        int oc = cb + i * 16 + lr;
        u16x4 o;
#pragma unroll
        for (int j = 0; j < 4; ++j)
            o[j] = f32_to_bf16(tile[lc4 + j][i * 16 + lr]);
        *(u16x4*)(out + (size_t)oc * R + rb + lc4) = o;
    }
}

// ---------------- pipelined bf16 GEMM: C[M][N] = A[M][K] * Bt[N][K]^T ----------------
template<int BN>
__global__ __launch_bounds__(512, 1)
void k_gemm256(const unsigned short* __restrict__ A, const unsigned short* __restrict__ Bt,
               float* __restrict__ C, int N, int K) {
    constexpr int ASZ = 8192;
    constexpr int BSZ = BN * 32;
    constexpr int NFRAG = BN / 64;
    __shared__ __align__(16) unsigned short As[4 * ASZ];
    __shared__ __align__(16) unsigned short Bs[4 * BSZ];
    const int tid = threadIdx.x;
    const int lane = tid & 63, wid = tid >> 6;
    const int g = lane >> 4, l15 = lane & 15;
    const int wave_m = wid >> 2, wave_n = wid & 3;
    const int nwg = gridDim.x, bid = blockIdx.x;
    const int swz = (bid & 7) * (nwg >> 3) + (bid >> 3);
    const int ntn = N / BN;
    const int bm = swz / ntn, bn = swz - bm * ntn;
    const int brow = bm << 8, bcol = bn * BN;

    const int rowS = ((tid >> 6) << 4) | (tid & 15);
    const int kcS = (tid >> 4) & 3;
    const unsigned short* sA = A + (size_t)(brow + rowS) * K + kcS * 8;
    const unsigned short* sB = Bt + (size_t)(bcol + rowS) * K + kcS * 8;

    const int aoff = (wave_m * 8 * 64 + g * 16 + l15) * 8;
    const int boff = (wave_n * NFRAG * 64 + g * 16 + l15) * 8;

    f32x4 acc[8][NFRAG] = {};
    const int nt = K >> 5;

    auto stageA = [&](int t) {
        unsigned short* d = As + (t & 3) * ASZ + tid * 8;
        const unsigned short* s = sA + (size_t)t * 32;
        gload16(s, d);
        gload16(s + (size_t)128 * K, d + 4096);
    };
    auto stageB = [&](int t) {
        unsigned short* d = Bs + (t & 3) * BSZ + tid * 8;
        const unsigned short* s = sB + (size_t)t * 32;
        gload16(s, d);
        if constexpr (BN == 256) gload16(s + (size_t)128 * K, d + 4096);
    };

    stageA(0); stageB(0); stageA(1); stageB(1); stageA(2); stageB(2);
    if constexpr (BN == 256) asm volatile("s_waitcnt vmcnt(8)" ::: "memory");
    else                     asm volatile("s_waitcnt vmcnt(6)" ::: "memory");
    __builtin_amdgcn_s_barrier();

    for (int t = 0; t < nt; ++t) {
        const int ba = (t & 3) * ASZ, bb = (t & 3) * BSZ;
        s16x8 af[4], bf[NFRAG];
#pragma unroll
        for (int f = 0; f < 4; ++f) af[f] = *(const s16x8*)(As + ba + aoff + f * 512);
#pragma unroll
        for (int j = 0; j < NFRAG; ++j) bf[j] = *(const s16x8*)(Bs + bb + boff + j * 512);
        if (t + 3 < nt) stageA(t + 3);
        __builtin_amdgcn_s_barrier();
        __builtin_amdgcn_s_setprio(1);
#pragma unroll
        for (int f = 0; f < 4; ++f)
#pragma unroll
            for (int j = 0; j < NFRAG; ++j)
                acc[f][j] = __builtin_amdgcn_mfma_f32_16x16x32_bf16(af[f], bf[j], acc[f][j], 0, 0, 0);
        __builtin_amdgcn_s_setprio(0);
        __builtin_amdgcn_s_barrier();
#pragma unroll
        for (int f = 0; f < 4; ++f) af[f] = *(const s16x8*)(As + ba + aoff + (4 + f) * 512);
        if (t + 3 < nt) stageB(t + 3);
        if (t + 3 < nt) {
            if constexpr (BN == 256) asm volatile("s_waitcnt vmcnt(8)" ::: "memory");
            else                     asm volatile("s_waitcnt vmcnt(6)" ::: "memory");
        } else if (t + 2 < nt) {
            if constexpr (BN == 256) asm volatile("s_waitcnt vmcnt(4)" ::: "memory");
            else                     asm volatile("s_waitcnt vmcnt(3)" ::: "memory");
        } else if (t + 1 < nt) {
            asm volatile("s_waitcnt vmcnt(0)" ::: "memory");
        }
        __builtin_amdgcn_s_barrier();
        __builtin_amdgcn_s_setprio(1);
#pragma unroll
        for (int f = 0; f < 4; ++f)
#pragma unroll
            for (int j = 0; j < NFRAG; ++j)
                acc[4 + f][j] = __builtin_amdgcn_mfma_f32_16x16x32_bf16(af[f], bf[j], acc[4 + f][j], 0, 0, 0);
        __builtin_amdgcn_s_setprio(0);
        __builtin_amdgcn_s_barrier();
    }

#pragma unroll
    for (int f = 0; f < 8; ++f)
#pragma unroll
        for (int j = 0; j < NFRAG; ++j)
#pragma unroll
            for (int r = 0; r < 4; ++r)
                C[(size_t)(brow + wave_m * 128 + f * 16 + g * 4 + r) * N
                  + bcol + wave_n * (BN / 4) + j * 16 + l15] = acc[f][j][r];
}

// ---------------- RoPE + pack Q/K, transpose V ----------------
__global__ void k_rope_pack(const float* __restrict__ qkv, const float* __restrict__ cosT,
                            const float* __restrict__ sinT, unsigned short* __restrict__ Qb,
                            unsigned short* __restrict__ Kb, unsigned short* __restrict__ Vt) {
    const int col = blockIdx.x * 256 + threadIdx.x;
    const int t = blockIdx.y;
    const float v = qkv[(size_t)t * 6144 + col];
    const int d = col & 127;
    if (col < 5120) {
        float o = v;
        if (d < 64) {
            float c = cosT[t * 64 + d], s = sinT[t * 64 + d];
            float partner = qkv[(size_t)t * 6144 + ((d < 32) ? col + 32 : col - 32)];
            o = (d < 32) ? (v * c - partner * s) : (v * c + partner * s);
        }
        unsigned short ob = f32_to_bf16(o);
        if (col < 4096) {
            int h = col >> 7;
            Qb[((size_t)h * 2048 + t) * 128 + d] = ob;
        } else {
            int hk = (col - 4096) >> 7;
            Kb[((size_t)hk * 2048 + t) * 128 + d] = ob;
        }
    } else {
        int hk = (col - 5120) >> 7;
        Vt[((size_t)hk * 128 + d) * 2048 + t] = f32_to_bf16(v);
    }
}

// ---------------- causal GQA flash attention (swapped QK^T, KVBLK=64, dbuf) ----------
// Q [32][2048][128], K [8][2048][128], Vt [8][128][2048] -> O bf16 [2048][4096]
// Block: 4 waves x 16 q-rows = 64 rows. LDS: K/V ring-2 (64KB) + per-wave P (8KB).
__global__ __launch_bounds__(256, 2)
void k_attn(const unsigned short* __restrict__ Qb, const unsigned short* __restrict__ Kb,
            const unsigned short* __restrict__ Vt, unsigned short* __restrict__ Ob) {
    __shared__ __align__(16) unsigned short Ks[2][8192];   // [dc16][key64][8]
    __shared__ __align__(16) unsigned short Vs[2][8192];   // [kc8][d128][8]
    __shared__ __align__(16) unsigned short Pl[4][1024];   // per-wave [q16][k64] XOR-swizzled
    const int h = blockIdx.y, hk = h >> 2;
    const int qb0 = blockIdx.x << 6;
    const int tid = threadIdx.x, lane = tid & 63, wid = tid >> 6;
    const int g = lane >> 4, l15 = lane & 15;
    const int qrow0 = qb0 + wid * 16;
    const int swz = (l15 & 7) << 4;

    // hoist Q fragments (B-operand: col=q=l15, k-chunk = kc*32 + g*8)
    s16x8 aq[4];
#pragma unroll
    for (int kc = 0; kc < 4; ++kc)
        aq[kc] = *(const s16x8*)(Qb + ((size_t)h * 2048 + qrow0 + l15) * 128 + kc * 32 + g * 8);

    const unsigned short* gK = Kb + ((size_t)hk * 2048 + (tid & 63)) * 128 + (tid >> 6) * 8;
    const unsigned short* gV = Vt + ((size_t)hk * 128 + (tid & 127)) * 2048 + (tid >> 7) * 8;

    auto stage = [&](int kb) {
        unsigned short* dK = Ks[kb & 1] + tid * 8;
        unsigned short* dV = Vs[kb & 1] + tid * 8;
        const unsigned short* sK = gK + (size_t)kb * 8192;
        const unsigned short* sV = gV + kb * 64;
#pragma unroll
        for (int i = 0; i < 4; ++i) gload16(sK + i * 32, dK + i * 2048);
#pragma unroll
        for (int i = 0; i < 4; ++i) gload16(sV + i * 16, dV + i * 2048);
    };

    f32x4 oacc[8] = {};
    float mr = -1e30f, lr = 0.f;
    const int nkb = (qb0 >> 6) + 1;
    stage(0);
    for (int kb = 0; kb < nkb; ++kb) {
        if (kb + 1 < nkb) {
            stage(kb + 1);
            asm volatile("s_waitcnt vmcnt(8)" ::: "memory");
        } else {
            asm volatile("s_waitcnt vmcnt(0)" ::: "memory");
        }
        __builtin_amdgcn_s_barrier();
        const unsigned short* ks = Ks[kb & 1];
        const unsigned short* vs = Vs[kb & 1];
        // S^T = K x Q (row = key, col = q): softmax becomes lane-local in q
        f32x4 s[4] = {};
#pragma unroll
        for (int kc = 0; kc < 4; ++kc)
#pragma unroll
            for (int kt = 0; kt < 4; ++kt) {
                s16x8 kf = *(const s16x8*)(ks + ((kc * 4 + g) * 64 + kt * 16 + l15) * 8);
                s[kt] = __builtin_amdgcn_mfma_f32_16x16x32_bf16(kf, aq[kc], s[kt], 0, 0, 0);
            }
        const int q = qrow0 + l15;
        if (kb * 64 + 63 > qrow0) {
#pragma unroll
            for (int kt = 0; kt < 4; ++kt)
#pragma unroll
                for (int r = 0; r < 4; ++r) {
                    float xv = s[kt][r] * SCALE_F;
                    s[kt][r] = (kb * 64 + kt * 16 + g * 4 + r > q) ? -3e38f : xv;
                }
        } else {
#pragma unroll
            for (int kt = 0; kt < 4; ++kt)
#pragma unroll
                for (int r = 0; r < 4; ++r) s[kt][r] *= SCALE_F;
        }
        float mx = -3e38f;
#pragma unroll
        for (int kt = 0; kt < 4; ++kt)
#pragma unroll
            for (int r = 0; r < 4; ++r) mx = fmaxf(mx, s[kt][r]);
        mx = fmaxf(mx, __shfl_xor(mx, 16));
        mx = fmaxf(mx, __shfl_xor(mx, 32));
        const float mnew = fmaxf(mr, mx);
        const float scal = __expf(mr - mnew);
        mr = mnew;
        float ps = 0.f;
#pragma unroll
        for (int kt = 0; kt < 4; ++kt)
#pragma unroll
            for (int r = 0; r < 4; ++r) {
                float p = __expf(s[kt][r] - mnew);
                s[kt][r] = p;
                ps += p;
            }
        ps += __shfl_xor(ps, 16);
        ps += __shfl_xor(ps, 32);
        lr = lr * scal + ps;
        float so[4];
#pragma unroll
        for (int r = 0; r < 4; ++r) so[r] = __shfl(scal, g * 4 + r, 16);
#pragma unroll
        for (int j = 0; j < 8; ++j) {
            oacc[j][0] *= so[0]; oacc[j][1] *= so[1];
            oacc[j][2] *= so[2]; oacc[j][3] *= so[3];
        }
        // P^T -> per-wave LDS [q16][k64], byte ^= (q&7)<<4
        char* pw = (char*)Pl[wid];
#pragma unroll
        for (int kt = 0; kt < 4; ++kt) {
            unsigned int w0 = (unsigned int)f32_to_bf16(s[kt][0]) | ((unsigned int)f32_to_bf16(s[kt][1]) << 16);
            unsigned int w1 = (unsigned int)f32_to_bf16(s[kt][2]) | ((unsigned int)f32_to_bf16(s[kt][3]) << 16);
            const int b0 = (l15 * 128 + kt * 32 + g * 8) ^ swz;
            *(unsigned int*)(pw + b0) = w0;
            *(unsigned int*)(pw + b0 + 4) = w1;
        }
        // PV: O[q][d] += P[q][k] * Vt[d][k]
#pragma unroll
        for (int kc = 0; kc < 2; ++kc) {
            s16x8 pa = *(const s16x8*)(pw + ((l15 * 128 + kc * 64 + g * 16) ^ swz));
#pragma unroll
            for (int j = 0; j < 8; ++j) {
                s16x8 bv = *(const s16x8*)(vs + ((kc * 4 + g) * 128 + j * 16 + l15) * 8);
                oacc[j] = __builtin_amdgcn_mfma_f32_16x16x32_bf16(pa, bv, oacc[j], 0, 0, 0);
            }
        }
        __builtin_amdgcn_s_barrier();
    }
    float li[4];
#pragma unroll
    for (int r = 0; r < 4; ++r) li[r] = 1.f / __shfl(lr, g * 4 + r, 16);
#pragma unroll
    for (int j = 0; j < 8; ++j)
#pragma unroll
        for (int r = 0; r < 4; ++r)
            Ob[(size_t)(qrow0 + g * 4 + r) * 4096 + h * 128 + j * 16 + l15] = f32_to_bf16(oacc[j][r] * li[r]);
}

extern "C" void kernel_launch(void* const* d_in, const int* in_sizes, int n_in,
                              void* d_out, int out_size, void* d_ws, size_t ws_size,
                              hipStream_t stream) {
    const float* x     = (const float*)d_in[0];
    const float* cosT  = (const float*)d_in[2];
    const float* sinT  = (const float*)d_in[3];
    const float* w_qkv = (const float*)d_in[4];
    const float* w_o   = (const float*)d_in[5];
    float* out = (float*)d_out;

    char* ws = (char*)d_ws;
    unsigned short* wT  = (unsigned short*)(ws + 0);
    float*          qkv = (float*)(ws + 50331648);
    unsigned short* Ob  = (unsigned short*)(ws + 50331648);
    unsigned short* xb  = (unsigned short*)(ws + 100663296);
    unsigned short* Qb  = xb;
    unsigned short* Kb  = (unsigned short*)(ws + 117440512);
    unsigned short* Vt  = (unsigned short*)(ws + 121634816);

    k_conv_bf16<<<8192, 256, 0, stream>>>(x, xb, 2097152);
    k_transpose_bf16<<<dim3(96, 64), 256, 0, stream>>>(w_qkv, wT, 4096, 6144);
    k_gemm256<256><<<192, 512, 0, stream>>>(xb, wT, qkv, 6144, 4096);
    k_rope_pack<<<dim3(24, 2048), 256, 0, stream>>>(qkv, cosT, sinT, Qb, Kb, Vt);
    k_transpose_bf16<<<dim3(64, 64), 256, 0, stream>>>(w_o, wT, 4096, 4096);
    k_attn<<<dim3(32, 32), 256, 0, stream>>>(Qb, Kb, Vt, Ob);
    k_gemm256<128><<<256, 512, 0, stream>>>(Ob, wT, out, 4096, 4096);
}

// Round 4
// 443.719 us; speedup vs baseline: 1.4028x; 1.1277x over previous
//
#include <hip/hip_runtime.h>
#include <stdint.h>

typedef float f32x4 __attribute__((ext_vector_type(4)));
typedef short s16x8 __attribute__((ext_vector_type(8)));
typedef unsigned short u16x4 __attribute__((ext_vector_type(4)));

#define SCALE_F 0.08838834764831845f

__device__ __forceinline__ unsigned short f32_to_bf16(float f) {
    union { float f; unsigned int u; } v; v.f = f;
    return (unsigned short)((v.u + 0x7FFFu + ((v.u >> 16) & 1u)) >> 16);
}

__device__ __forceinline__ void gload16(const void* g, void* l) {
    __builtin_amdgcn_global_load_lds((const __attribute__((address_space(1))) unsigned int*)g,
                                     (__attribute__((address_space(3))) unsigned int*)l,
                                     16, 0, 0);
}

// ---------------- fp32 -> bf16 elementwise ----------------
__global__ void k_conv_bf16(const float* __restrict__ in, unsigned short* __restrict__ out, int n4) {
    int i = blockIdx.x * 256 + threadIdx.x;
    if (i >= n4) return;
    f32x4 v = ((const f32x4*)in)[i];
    u16x4 o;
    o[0] = f32_to_bf16(v[0]); o[1] = f32_to_bf16(v[1]);
    o[2] = f32_to_bf16(v[2]); o[3] = f32_to_bf16(v[3]);
    ((u16x4*)out)[i] = o;
}

// ---------------- fp32 [R][C] -> bf16 [C][R] transpose ----------------
__global__ void k_transpose_bf16(const float* __restrict__ in, unsigned short* __restrict__ out,
                                 int R, int C) {
    __shared__ float tile[64][65];
    const int rb = blockIdx.y * 64, cb = blockIdx.x * 64;
    const int t = threadIdx.x;
    const int lr = t >> 4, lc4 = (t & 15) * 4;
#pragma unroll
    for (int i = 0; i < 4; ++i) {
        int r = i * 16 + lr;
        f32x4 v = *(const f32x4*)(in + (size_t)(rb + r) * C + cb + lc4);
        tile[r][lc4 + 0] = v[0]; tile[r][lc4 + 1] = v[1];
        tile[r][lc4 + 2] = v[2]; tile[r][lc4 + 3] = v[3];
    }
    __syncthreads();
#pragma unroll
    for (int i = 0; i < 4; ++i) {
        int oc = cb + i * 16 + lr;
        u16x4 o;
#pragma unroll
        for (int j = 0; j < 4; ++j)
            o[j] = f32_to_bf16(tile[lc4 + j][i * 16 + lr]);
        *(u16x4*)(out + (size_t)oc * R + rb + lc4) = o;
    }
}

// ---------------- K-half-phase pipelined bf16 GEMM ----------------
// C[M][N] = A[M][K] * Bt[N][K]^T.  BM=256, BK=64 (2 K-halves of 32), ring-2.
// 512 thr = 8 waves (2M x 4N). Per phase: {stage 1 half of t+1; counted vmcnt;
// barrier (phases 0/2 only for BN=256); ds_read frags; setprio; 16 MFMA}.
// LDS slot-swizzle: slot = kchunk ^ (row&3) ^ ((row>>2)&3), applied on the
// global source for staging and on the (per-thread-constant) frag read offset.
template<int BN>
__global__ __launch_bounds__(512, 1)
void k_gemm8p(const unsigned short* __restrict__ A, const unsigned short* __restrict__ Bt,
              float* __restrict__ C, int N, int K) {
    constexpr int BH = BN * 32;        // shorts per B K-half
    constexpr int NF = BN / 64;        // B-frags per wave per kc
    __shared__ __align__(16) unsigned short As[2][2][8192];
    __shared__ __align__(16) unsigned short Bs[2][2][BH];
    const int tid = threadIdx.x;
    const int lane = tid & 63, wid = tid >> 6;
    const int g = lane >> 4, l15 = lane & 15;
    const int wm = wid >> 2, wn = wid & 3;
    const int nwg = gridDim.x, bid = blockIdx.x;
    const int swz = (bid & 7) * (nwg >> 3) + (bid >> 3);   // bijective: nwg % 8 == 0
    const int ntn = N / BN;
    const int bm = swz / ntn, bn = swz - bm * ntn;
    const int brow = bm << 8, bcol = bn * BN;

    // staging: thread -> row rS (+128 for pass 1), swizzled k-chunk kcS (same both passes)
    const int rS = tid >> 2;
    const int kcS = (tid & 3) ^ (rS & 3) ^ ((rS >> 2) & 3);
    const unsigned short* sA = A + (size_t)(brow + rS) * K + kcS * 8;
    const unsigned short* sB = Bt + (size_t)(bcol + rS) * K + kcS * 8;
    // frag-read swizzled slot offset (shorts) — per-thread constant
    const int fsw = (g ^ (l15 & 3) ^ ((l15 >> 2) & 3)) * 8;

    f32x4 acc[8][NF] = {};
    const int nt = K >> 6;

    auto stA = [&](int t, int kh) {
        unsigned short* d = &As[t & 1][kh][tid * 8];
        const unsigned short* s = sA + (size_t)t * 64 + kh * 32;
        gload16(s, d);
        gload16(s + (size_t)128 * K, d + 4096);
    };
    auto stB = [&](int t, int kh) {
        unsigned short* d = &Bs[t & 1][kh][tid * 8];
        const unsigned short* s = sB + (size_t)t * 64 + kh * 32;
        gload16(s, d);
        if constexpr (BN == 256) gload16(s + (size_t)128 * K, d + 4096);
    };

    // prologue: tile 0 fully staged (order A0,B0,A1,B1 — matches steady-state)
    stA(0, 0); stB(0, 0); stA(0, 1); stB(0, 1);

    for (int t = 0; t < nt; ++t) {
        const int c = t & 1;
        if constexpr (BN == 256) {
            s16x8 af[4], bf[4];
            // ---- P0: kh0 x rows 0-63 ----
            if (t + 1 < nt) { stA(t + 1, 0); asm volatile("s_waitcnt vmcnt(6)" ::: "memory"); }
            else            { asm volatile("s_waitcnt vmcnt(4)" ::: "memory"); }
            __builtin_amdgcn_s_barrier();
#pragma unroll
            for (int f = 0; f < 4; ++f)
                af[f] = *(const s16x8*)(&As[c][0][(wm * 128 + f * 16 + l15) * 32 + fsw]);
#pragma unroll
            for (int j = 0; j < 4; ++j)
                bf[j] = *(const s16x8*)(&Bs[c][0][(wn * 64 + j * 16 + l15) * 32 + fsw]);
            __builtin_amdgcn_s_setprio(1);
#pragma unroll
            for (int f = 0; f < 4; ++f)
#pragma unroll
                for (int j = 0; j < 4; ++j)
                    acc[f][j] = __builtin_amdgcn_mfma_f32_16x16x32_bf16(af[f], bf[j], acc[f][j], 0, 0, 0);
            __builtin_amdgcn_s_setprio(0);
            // ---- P1: kh0 x rows 64-127 (B frags reused in regs) ----
            if (t + 1 < nt) stB(t + 1, 0);
#pragma unroll
            for (int f = 0; f < 4; ++f)
                af[f] = *(const s16x8*)(&As[c][0][(wm * 128 + 64 + f * 16 + l15) * 32 + fsw]);
            __builtin_amdgcn_s_setprio(1);
#pragma unroll
            for (int f = 0; f < 4; ++f)
#pragma unroll
                for (int j = 0; j < 4; ++j)
                    acc[4 + f][j] = __builtin_amdgcn_mfma_f32_16x16x32_bf16(af[f], bf[j], acc[4 + f][j], 0, 0, 0);
            __builtin_amdgcn_s_setprio(0);
            // ---- P2: kh1 x rows 0-63 ----
            if (t + 1 < nt) { stA(t + 1, 1); asm volatile("s_waitcnt vmcnt(6)" ::: "memory"); }
            else            { asm volatile("s_waitcnt vmcnt(0)" ::: "memory"); }
            __builtin_amdgcn_s_barrier();
#pragma unroll
            for (int f = 0; f < 4; ++f)
                af[f] = *(const s16x8*)(&As[c][1][(wm * 128 + f * 16 + l15) * 32 + fsw]);
#pragma unroll
            for (int j = 0; j < 4; ++j)
                bf[j] = *(const s16x8*)(&Bs[c][1][(wn * 64 + j * 16 + l15) * 32 + fsw]);
            __builtin_amdgcn_s_setprio(1);
#pragma unroll
            for (int f = 0; f < 4; ++f)
#pragma unroll
                for (int j = 0; j < 4; ++j)
                    acc[f][j] = __builtin_amdgcn_mfma_f32_16x16x32_bf16(af[f], bf[j], acc[f][j], 0, 0, 0);
            __builtin_amdgcn_s_setprio(0);
            // ---- P3: kh1 x rows 64-127 ----
            if (t + 1 < nt) stB(t + 1, 1);
#pragma unroll
            for (int f = 0; f < 4; ++f)
                af[f] = *(const s16x8*)(&As[c][1][(wm * 128 + 64 + f * 16 + l15) * 32 + fsw]);
            __builtin_amdgcn_s_setprio(1);
#pragma unroll
            for (int f = 0; f < 4; ++f)
#pragma unroll
                for (int j = 0; j < 4; ++j)
                    acc[4 + f][j] = __builtin_amdgcn_mfma_f32_16x16x32_bf16(af[f], bf[j], acc[4 + f][j], 0, 0, 0);
            __builtin_amdgcn_s_setprio(0);
        } else {
            s16x8 af[8], bf[2];
            // ---- P0: kh0, all 8 row-frags ----
            if (t + 1 < nt) { stA(t + 1, 0); stB(t + 1, 0); asm volatile("s_waitcnt vmcnt(6)" ::: "memory"); }
            else            { asm volatile("s_waitcnt vmcnt(3)" ::: "memory"); }
            __builtin_amdgcn_s_barrier();
#pragma unroll
            for (int f = 0; f < 8; ++f)
                af[f] = *(const s16x8*)(&As[c][0][(wm * 128 + f * 16 + l15) * 32 + fsw]);
#pragma unroll
            for (int j = 0; j < 2; ++j)
                bf[j] = *(const s16x8*)(&Bs[c][0][(wn * 32 + j * 16 + l15) * 32 + fsw]);
            __builtin_amdgcn_s_setprio(1);
#pragma unroll
            for (int f = 0; f < 8; ++f)
#pragma unroll
                for (int j = 0; j < 2; ++j)
                    acc[f][j] = __builtin_amdgcn_mfma_f32_16x16x32_bf16(af[f], bf[j], acc[f][j], 0, 0, 0);
            __builtin_amdgcn_s_setprio(0);
            // ---- P1: kh1 ----
            if (t + 1 < nt) { stA(t + 1, 1); stB(t + 1, 1); asm volatile("s_waitcnt vmcnt(6)" ::: "memory"); }
            else            { asm volatile("s_waitcnt vmcnt(0)" ::: "memory"); }
            __builtin_amdgcn_s_barrier();
#pragma unroll
            for (int f = 0; f < 8; ++f)
                af[f] = *(const s16x8*)(&As[c][1][(wm * 128 + f * 16 + l15) * 32 + fsw]);
#pragma unroll
            for (int j = 0; j < 2; ++j)
                bf[j] = *(const s16x8*)(&Bs[c][1][(wn * 32 + j * 16 + l15) * 32 + fsw]);
            __builtin_amdgcn_s_setprio(1);
#pragma unroll
            for (int f = 0; f < 8; ++f)
#pragma unroll
                for (int j = 0; j < 2; ++j)
                    acc[f][j] = __builtin_amdgcn_mfma_f32_16x16x32_bf16(af[f], bf[j], acc[f][j], 0, 0, 0);
            __builtin_amdgcn_s_setprio(0);
        }
    }

#pragma unroll
    for (int f = 0; f < 8; ++f)
#pragma unroll
        for (int j = 0; j < NF; ++j)
#pragma unroll
            for (int r = 0; r < 4; ++r)
                C[(size_t)(brow + wm * 128 + f * 16 + g * 4 + r) * N
                  + bcol + wn * (BN / 4) + j * 16 + l15] = acc[f][j][r];
}

// ---------------- RoPE + pack Q/K, transpose V ----------------
__global__ void k_rope_pack(const float* __restrict__ qkv, const float* __restrict__ cosT,
                            const float* __restrict__ sinT, unsigned short* __restrict__ Qb,
                            unsigned short* __restrict__ Kb, unsigned short* __restrict__ Vt) {
    const int col = blockIdx.x * 256 + threadIdx.x;
    const int t = blockIdx.y;
    const float v = qkv[(size_t)t * 6144 + col];
    const int d = col & 127;
    if (col < 5120) {
        float o = v;
        if (d < 64) {
            float c = cosT[t * 64 + d], s = sinT[t * 64 + d];
            float partner = qkv[(size_t)t * 6144 + ((d < 32) ? col + 32 : col - 32)];
            o = (d < 32) ? (v * c - partner * s) : (v * c + partner * s);
        }
        unsigned short ob = f32_to_bf16(o);
        if (col < 4096) {
            int h = col >> 7;
            Qb[((size_t)h * 2048 + t) * 128 + d] = ob;
        } else {
            int hk = (col - 4096) >> 7;
            Kb[((size_t)hk * 2048 + t) * 128 + d] = ob;
        }
    } else {
        int hk = (col - 5120) >> 7;
        Vt[((size_t)hk * 128 + d) * 2048 + t] = f32_to_bf16(v);
    }
}

// ---------------- causal GQA flash attention (swapped QK^T, KVBLK=64, dbuf) ----------
__global__ __launch_bounds__(256, 2)
void k_attn(const unsigned short* __restrict__ Qb, const unsigned short* __restrict__ Kb,
            const unsigned short* __restrict__ Vt, unsigned short* __restrict__ Ob) {
    __shared__ __align__(16) unsigned short Ks[2][8192];
    __shared__ __align__(16) unsigned short Vs[2][8192];
    __shared__ __align__(16) unsigned short Pl[4][1024];
    const int h = blockIdx.y, hk = h >> 2;
    const int qb0 = blockIdx.x << 6;
    const int tid = threadIdx.x, lane = tid & 63, wid = tid >> 6;
    const int g = lane >> 4, l15 = lane & 15;
    const int qrow0 = qb0 + wid * 16;
    const int swz = (l15 & 7) << 4;

    s16x8 aq[4];
#pragma unroll
    for (int kc = 0; kc < 4; ++kc)
        aq[kc] = *(const s16x8*)(Qb + ((size_t)h * 2048 + qrow0 + l15) * 128 + kc * 32 + g * 8);

    const unsigned short* gK = Kb + ((size_t)hk * 2048 + (tid & 63)) * 128 + (tid >> 6) * 8;
    const unsigned short* gV = Vt + ((size_t)hk * 128 + (tid & 127)) * 2048 + (tid >> 7) * 8;

    auto stage = [&](int kb) {
        unsigned short* dK = Ks[kb & 1] + tid * 8;
        unsigned short* dV = Vs[kb & 1] + tid * 8;
        const unsigned short* sK = gK + (size_t)kb * 8192;
        const unsigned short* sV = gV + kb * 64;
#pragma unroll
        for (int i = 0; i < 4; ++i) gload16(sK + i * 32, dK + i * 2048);
#pragma unroll
        for (int i = 0; i < 4; ++i) gload16(sV + i * 16, dV + i * 2048);
    };

    f32x4 oacc[8] = {};
    float mr = -1e30f, lr = 0.f;
    const int nkb = (qb0 >> 6) + 1;
    stage(0);
    for (int kb = 0; kb < nkb; ++kb) {
        if (kb + 1 < nkb) {
            stage(kb + 1);
            asm volatile("s_waitcnt vmcnt(8)" ::: "memory");
        } else {
            asm volatile("s_waitcnt vmcnt(0)" ::: "memory");
        }
        __builtin_amdgcn_s_barrier();
        const unsigned short* ks = Ks[kb & 1];
        const unsigned short* vs = Vs[kb & 1];
        f32x4 s[4] = {};
#pragma unroll
        for (int kc = 0; kc < 4; ++kc)
#pragma unroll
            for (int kt = 0; kt < 4; ++kt) {
                s16x8 kf = *(const s16x8*)(ks + ((kc * 4 + g) * 64 + kt * 16 + l15) * 8);
                s[kt] = __builtin_amdgcn_mfma_f32_16x16x32_bf16(kf, aq[kc], s[kt], 0, 0, 0);
            }
        const int q = qrow0 + l15;
        if (kb * 64 + 63 > qrow0) {
#pragma unroll
            for (int kt = 0; kt < 4; ++kt)
#pragma unroll
                for (int r = 0; r < 4; ++r) {
                    float xv = s[kt][r] * SCALE_F;
                    s[kt][r] = (kb * 64 + kt * 16 + g * 4 + r > q) ? -3e38f : xv;
                }
        } else {
#pragma unroll
            for (int kt = 0; kt < 4; ++kt)
#pragma unroll
                for (int r = 0; r < 4; ++r) s[kt][r] *= SCALE_F;
        }
        float mx = -3e38f;
#pragma unroll
        for (int kt = 0; kt < 4; ++kt)
#pragma unroll
            for (int r = 0; r < 4; ++r) mx = fmaxf(mx, s[kt][r]);
        mx = fmaxf(mx, __shfl_xor(mx, 16));
        mx = fmaxf(mx, __shfl_xor(mx, 32));
        const float mnew = fmaxf(mr, mx);
        const float scal = __expf(mr - mnew);
        mr = mnew;
        float ps = 0.f;
#pragma unroll
        for (int kt = 0; kt < 4; ++kt)
#pragma unroll
            for (int r = 0; r < 4; ++r) {
                float p = __expf(s[kt][r] - mnew);
                s[kt][r] = p;
                ps += p;
            }
        ps += __shfl_xor(ps, 16);
        ps += __shfl_xor(ps, 32);
        lr = lr * scal + ps;
        float so[4];
#pragma unroll
        for (int r = 0; r < 4; ++r) so[r] = __shfl(scal, g * 4 + r, 16);
#pragma unroll
        for (int j = 0; j < 8; ++j) {
            oacc[j][0] *= so[0]; oacc[j][1] *= so[1];
            oacc[j][2] *= so[2]; oacc[j][3] *= so[3];
        }
        char* pw = (char*)Pl[wid];
#pragma unroll
        for (int kt = 0; kt < 4; ++kt) {
            unsigned int w0 = (unsigned int)f32_to_bf16(s[kt][0]) | ((unsigned int)f32_to_bf16(s[kt][1]) << 16);
            unsigned int w1 = (unsigned int)f32_to_bf16(s[kt][2]) | ((unsigned int)f32_to_bf16(s[kt][3]) << 16);
            const int b0 = (l15 * 128 + kt * 32 + g * 8) ^ swz;
            *(unsigned int*)(pw + b0) = w0;
            *(unsigned int*)(pw + b0 + 4) = w1;
        }
#pragma unroll
        for (int kc = 0; kc < 2; ++kc) {
            s16x8 pa = *(const s16x8*)(pw + ((l15 * 128 + kc * 64 + g * 16) ^ swz));
#pragma unroll
            for (int j = 0; j < 8; ++j) {
                s16x8 bv = *(const s16x8*)(vs + ((kc * 4 + g) * 128 + j * 16 + l15) * 8);
                oacc[j] = __builtin_amdgcn_mfma_f32_16x16x32_bf16(pa, bv, oacc[j], 0, 0, 0);
            }
        }
        __builtin_amdgcn_s_barrier();
    }
    float li[4];
#pragma unroll
    for (int r = 0; r < 4; ++r) li[r] = 1.f / __shfl(lr, g * 4 + r, 16);
#pragma unroll
    for (int j = 0; j < 8; ++j)
#pragma unroll
        for (int r = 0; r < 4; ++r)
            Ob[(size_t)(qrow0 + g * 4 + r) * 4096 + h * 128 + j * 16 + l15] = f32_to_bf16(oacc[j][r] * li[r]);
}

extern "C" void kernel_launch(void* const* d_in, const int* in_sizes, int n_in,
                              void* d_out, int out_size, void* d_ws, size_t ws_size,
                              hipStream_t stream) {
    const float* x     = (const float*)d_in[0];
    const float* cosT  = (const float*)d_in[2];
    const float* sinT  = (const float*)d_in[3];
    const float* w_qkv = (const float*)d_in[4];
    const float* w_o   = (const float*)d_in[5];
    float* out = (float*)d_out;

    char* ws = (char*)d_ws;
    unsigned short* wT  = (unsigned short*)(ws + 0);
    float*          qkv = (float*)(ws + 50331648);
    unsigned short* Ob  = (unsigned short*)(ws + 50331648);
    unsigned short* xb  = (unsigned short*)(ws + 100663296);
    unsigned short* Qb  = xb;
    unsigned short* Kb  = (unsigned short*)(ws + 117440512);
    unsigned short* Vt  = (unsigned short*)(ws + 121634816);

    k_conv_bf16<<<8192, 256, 0, stream>>>(x, xb, 2097152);
    k_transpose_bf16<<<dim3(96, 64), 256, 0, stream>>>(w_qkv, wT, 4096, 6144);
    k_gemm8p<256><<<192, 512, 0, stream>>>(xb, wT, qkv, 6144, 4096);
    k_rope_pack<<<dim3(24, 2048), 256, 0, stream>>>(qkv, cosT, sinT, Qb, Kb, Vt);
    k_transpose_bf16<<<dim3(64, 64), 256, 0, stream>>>(w_o, wT, 4096, 4096);
    k_attn<<<dim3(32, 32), 256, 0, stream>>>(Qb, Kb, Vt, Ob);
    k_gemm8p<128><<<256, 512, 0, stream>>>(Ob, wT, out, 4096, 4096);
}

// Round 5
// 411.603 us; speedup vs baseline: 1.5123x; 1.0780x over previous
//
#include <hip/hip_runtime.h>
#include <stdint.h>

typedef float f32x4 __attribute__((ext_vector_type(4)));
typedef short s16x8 __attribute__((ext_vector_type(8)));
typedef unsigned short u16x4 __attribute__((ext_vector_type(4)));

#define SCALE_F 0.08838834764831845f

__device__ __forceinline__ unsigned short f32_to_bf16(float f) {
    union { float f; unsigned int u; } v; v.f = f;
    return (unsigned short)((v.u + 0x7FFFu + ((v.u >> 16) & 1u)) >> 16);
}

__device__ __forceinline__ void gload16(const void* g, void* l) {
    __builtin_amdgcn_global_load_lds((const __attribute__((address_space(1))) unsigned int*)g,
                                     (__attribute__((address_space(3))) unsigned int*)l,
                                     16, 0, 0);
}

// ---------------- fp32 -> bf16 elementwise ----------------
__global__ void k_conv_bf16(const float* __restrict__ in, unsigned short* __restrict__ out, int n4) {
    int i = blockIdx.x * 256 + threadIdx.x;
    if (i >= n4) return;
    f32x4 v = ((const f32x4*)in)[i];
    u16x4 o;
    o[0] = f32_to_bf16(v[0]); o[1] = f32_to_bf16(v[1]);
    o[2] = f32_to_bf16(v[2]); o[3] = f32_to_bf16(v[3]);
    ((u16x4*)out)[i] = o;
}

// ------- fp32 [R][C] (row stride in_ld, col offset in_off) -> bf16 [C][R] -------
__global__ void k_transpose_bf16(const float* __restrict__ in, unsigned short* __restrict__ out,
                                 int R, int in_ld, int in_off) {
    __shared__ float tile[64][65];
    const int rb = blockIdx.y * 64, cb = blockIdx.x * 64;
    const int t = threadIdx.x;
    const int lr = t >> 4, lc4 = (t & 15) * 4;
#pragma unroll
    for (int i = 0; i < 4; ++i) {
        int r = i * 16 + lr;
        f32x4 v = *(const f32x4*)(in + (size_t)(rb + r) * in_ld + in_off + cb + lc4);
        tile[r][lc4 + 0] = v[0]; tile[r][lc4 + 1] = v[1];
        tile[r][lc4 + 2] = v[2]; tile[r][lc4 + 3] = v[3];
    }
    __syncthreads();
#pragma unroll
    for (int i = 0; i < 4; ++i) {
        int oc = cb + i * 16 + lr;
        u16x4 o;
#pragma unroll
        for (int j = 0; j < 4; ++j)
            o[j] = f32_to_bf16(tile[lc4 + j][i * 16 + lr]);
        *(u16x4*)(out + (size_t)oc * R + rb + lc4) = o;
    }
}

// ---------------- K-half-phase pipelined bf16 GEMM ----------------
template<int BN>
__global__ __launch_bounds__(512, 1)
void k_gemm8p(const unsigned short* __restrict__ A, const unsigned short* __restrict__ Bt,
              float* __restrict__ C, int N, int K) {
    constexpr int BH = BN * 32;
    constexpr int NF = BN / 64;
    __shared__ __align__(16) unsigned short As[2][2][8192];
    __shared__ __align__(16) unsigned short Bs[2][2][BH];
    const int tid = threadIdx.x;
    const int lane = tid & 63, wid = tid >> 6;
    const int g = lane >> 4, l15 = lane & 15;
    const int wm = wid >> 2, wn = wid & 3;
    const int nwg = gridDim.x, bid = blockIdx.x;
    const int swz = (bid & 7) * (nwg >> 3) + (bid >> 3);
    const int ntn = N / BN;
    const int bm = swz / ntn, bn = swz - bm * ntn;
    const int brow = bm << 8, bcol = bn * BN;

    const int rS = tid >> 2;
    const int kcS = (tid & 3) ^ (rS & 3) ^ ((rS >> 2) & 3);
    const unsigned short* sA = A + (size_t)(brow + rS) * K + kcS * 8;
    const unsigned short* sB = Bt + (size_t)(bcol + rS) * K + kcS * 8;
    const int fsw = (g ^ (l15 & 3) ^ ((l15 >> 2) & 3)) * 8;

    f32x4 acc[8][NF] = {};
    const int nt = K >> 6;

    auto stA = [&](int t, int kh) {
        unsigned short* d = &As[t & 1][kh][tid * 8];
        const unsigned short* s = sA + (size_t)t * 64 + kh * 32;
        gload16(s, d);
        gload16(s + (size_t)128 * K, d + 4096);
    };
    auto stB = [&](int t, int kh) {
        unsigned short* d = &Bs[t & 1][kh][tid * 8];
        const unsigned short* s = sB + (size_t)t * 64 + kh * 32;
        gload16(s, d);
        if constexpr (BN == 256) gload16(s + (size_t)128 * K, d + 4096);
    };

    stA(0, 0); stB(0, 0); stA(0, 1); stB(0, 1);

    for (int t = 0; t < nt; ++t) {
        const int c = t & 1;
        if constexpr (BN == 256) {
            s16x8 af[4], bf[4];
            if (t + 1 < nt) { stA(t + 1, 0); asm volatile("s_waitcnt vmcnt(6)" ::: "memory"); }
            else            { asm volatile("s_waitcnt vmcnt(4)" ::: "memory"); }
            __builtin_amdgcn_s_barrier();
#pragma unroll
            for (int f = 0; f < 4; ++f)
                af[f] = *(const s16x8*)(&As[c][0][(wm * 128 + f * 16 + l15) * 32 + fsw]);
#pragma unroll
            for (int j = 0; j < 4; ++j)
                bf[j] = *(const s16x8*)(&Bs[c][0][(wn * 64 + j * 16 + l15) * 32 + fsw]);
            __builtin_amdgcn_s_setprio(1);
#pragma unroll
            for (int f = 0; f < 4; ++f)
#pragma unroll
                for (int j = 0; j < 4; ++j)
                    acc[f][j] = __builtin_amdgcn_mfma_f32_16x16x32_bf16(af[f], bf[j], acc[f][j], 0, 0, 0);
            __builtin_amdgcn_s_setprio(0);
            if (t + 1 < nt) stB(t + 1, 0);
#pragma unroll
            for (int f = 0; f < 4; ++f)
                af[f] = *(const s16x8*)(&As[c][0][(wm * 128 + 64 + f * 16 + l15) * 32 + fsw]);
            __builtin_amdgcn_s_setprio(1);
#pragma unroll
            for (int f = 0; f < 4; ++f)
#pragma unroll
                for (int j = 0; j < 4; ++j)
                    acc[4 + f][j] = __builtin_amdgcn_mfma_f32_16x16x32_bf16(af[f], bf[j], acc[4 + f][j], 0, 0, 0);
            __builtin_amdgcn_s_setprio(0);
            if (t + 1 < nt) { stA(t + 1, 1); asm volatile("s_waitcnt vmcnt(6)" ::: "memory"); }
            else            { asm volatile("s_waitcnt vmcnt(0)" ::: "memory"); }
            __builtin_amdgcn_s_barrier();
#pragma unroll
            for (int f = 0; f < 4; ++f)
                af[f] = *(const s16x8*)(&As[c][1][(wm * 128 + f * 16 + l15) * 32 + fsw]);
#pragma unroll
            for (int j = 0; j < 4; ++j)
                bf[j] = *(const s16x8*)(&Bs[c][1][(wn * 64 + j * 16 + l15) * 32 + fsw]);
            __builtin_amdgcn_s_setprio(1);
#pragma unroll
            for (int f = 0; f < 4; ++f)
#pragma unroll
                for (int j = 0; j < 4; ++j)
                    acc[f][j] = __builtin_amdgcn_mfma_f32_16x16x32_bf16(af[f], bf[j], acc[f][j], 0, 0, 0);
            __builtin_amdgcn_s_setprio(0);
            if (t + 1 < nt) stB(t + 1, 1);
#pragma unroll
            for (int f = 0; f < 4; ++f)
                af[f] = *(const s16x8*)(&As[c][1][(wm * 128 + 64 + f * 16 + l15) * 32 + fsw]);
            __builtin_amdgcn_s_setprio(1);
#pragma unroll
            for (int f = 0; f < 4; ++f)
#pragma unroll
                for (int j = 0; j < 4; ++j)
                    acc[4 + f][j] = __builtin_amdgcn_mfma_f32_16x16x32_bf16(af[f], bf[j], acc[4 + f][j], 0, 0, 0);
            __builtin_amdgcn_s_setprio(0);
        } else {
            s16x8 af[8], bf[2];
            if (t + 1 < nt) { stA(t + 1, 0); stB(t + 1, 0); asm volatile("s_waitcnt vmcnt(6)" ::: "memory"); }
            else            { asm volatile("s_waitcnt vmcnt(3)" ::: "memory"); }
            __builtin_amdgcn_s_barrier();
#pragma unroll
            for (int f = 0; f < 8; ++f)
                af[f] = *(const s16x8*)(&As[c][0][(wm * 128 + f * 16 + l15) * 32 + fsw]);
#pragma unroll
            for (int j = 0; j < 2; ++j)
                bf[j] = *(const s16x8*)(&Bs[c][0][(wn * 32 + j * 16 + l15) * 32 + fsw]);
            __builtin_amdgcn_s_setprio(1);
#pragma unroll
            for (int f = 0; f < 8; ++f)
#pragma unroll
                for (int j = 0; j < 2; ++j)
                    acc[f][j] = __builtin_amdgcn_mfma_f32_16x16x32_bf16(af[f], bf[j], acc[f][j], 0, 0, 0);
            __builtin_amdgcn_s_setprio(0);
            if (t + 1 < nt) { stA(t + 1, 1); stB(t + 1, 1); asm volatile("s_waitcnt vmcnt(6)" ::: "memory"); }
            else            { asm volatile("s_waitcnt vmcnt(0)" ::: "memory"); }
            __builtin_amdgcn_s_barrier();
#pragma unroll
            for (int f = 0; f < 8; ++f)
                af[f] = *(const s16x8*)(&As[c][1][(wm * 128 + f * 16 + l15) * 32 + fsw]);
#pragma unroll
            for (int j = 0; j < 2; ++j)
                bf[j] = *(const s16x8*)(&Bs[c][1][(wn * 32 + j * 16 + l15) * 32 + fsw]);
            __builtin_amdgcn_s_setprio(1);
#pragma unroll
            for (int f = 0; f < 8; ++f)
#pragma unroll
                for (int j = 0; j < 2; ++j)
                    acc[f][j] = __builtin_amdgcn_mfma_f32_16x16x32_bf16(af[f], bf[j], acc[f][j], 0, 0, 0);
            __builtin_amdgcn_s_setprio(0);
        }
    }

#pragma unroll
    for (int f = 0; f < 8; ++f)
#pragma unroll
        for (int j = 0; j < NF; ++j)
#pragma unroll
            for (int r = 0; r < 4; ++r)
                C[(size_t)(brow + wm * 128 + f * 16 + g * 4 + r) * N
                  + bcol + wn * (BN / 4) + j * 16 + l15] = acc[f][j][r];
}

// ---------------- RoPE + pack Q/K (V handled by transpose kernel) ----------------
__global__ void k_rope_pack(const float* __restrict__ qkv, const float* __restrict__ cosT,
                            const float* __restrict__ sinT, unsigned short* __restrict__ Qb,
                            unsigned short* __restrict__ Kb) {
    const int col = blockIdx.x * 256 + threadIdx.x;  // 0..5119
    const int t = blockIdx.y;
    const float v = qkv[(size_t)t * 6144 + col];
    const int d = col & 127;
    float o = v;
    if (d < 64) {
        float c = cosT[t * 64 + d], s = sinT[t * 64 + d];
        float partner = qkv[(size_t)t * 6144 + ((d < 32) ? col + 32 : col - 32)];
        o = (d < 32) ? (v * c - partner * s) : (v * c + partner * s);
    }
    unsigned short ob = f32_to_bf16(o);
    if (col < 4096) {
        int h = col >> 7;
        Qb[((size_t)h * 2048 + t) * 128 + d] = ob;
    } else {
        int hk = (col - 4096) >> 7;
        Kb[((size_t)hk * 2048 + t) * 128 + d] = ob;
    }
}

// ------- causal GQA flash attention: paired q-tiles (qbA, 31-qbA), shared K/V pass -------
// Q [32][2048][128], K [8][2048][128], Vt [8][128][2048] -> O bf16 [2048][4096]
// Grid (16, 32) = 512 blocks, uniform 33 tile-computes each; 4 waves; LDS 80KB -> 2 blk/CU.
__global__ __launch_bounds__(256, 2)
void k_attn(const unsigned short* __restrict__ Qb, const unsigned short* __restrict__ Kb,
            const unsigned short* __restrict__ Vt, unsigned short* __restrict__ Ob) {
    __shared__ __align__(16) unsigned short Ks[2][8192];   // [dc16][key64][8]
    __shared__ __align__(16) unsigned short Vs[2][8192];   // [kc8][d128][8]
    __shared__ __align__(16) unsigned short Pl[2][4][1024];
    const int h = blockIdx.y, hk = h >> 2;
    const int qbA = blockIdx.x, qbB = 31 - qbA;
    const int tid = threadIdx.x, lane = tid & 63, wid = tid >> 6;
    const int g = lane >> 4, l15 = lane & 15;
    const int qrA = qbA * 64 + wid * 16, qrB = qbB * 64 + wid * 16;
    const int swz = (l15 & 7) << 4;

    s16x8 aqA[4], aqB[4];
#pragma unroll
    for (int kc = 0; kc < 4; ++kc) {
        aqA[kc] = *(const s16x8*)(Qb + ((size_t)h * 2048 + qrA + l15) * 128 + kc * 32 + g * 8);
        aqB[kc] = *(const s16x8*)(Qb + ((size_t)h * 2048 + qrB + l15) * 128 + kc * 32 + g * 8);
    }

    const unsigned short* gK = Kb + ((size_t)hk * 2048 + (tid & 63)) * 128 + (tid >> 6) * 8;
    const unsigned short* gV = Vt + ((size_t)hk * 128 + (tid & 127)) * 2048 + (tid >> 7) * 8;

    auto stage = [&](int kb) {
        unsigned short* dK = Ks[kb & 1] + tid * 8;
        unsigned short* dV = Vs[kb & 1] + tid * 8;
        const unsigned short* sK = gK + (size_t)kb * 8192;
        const unsigned short* sV = gV + kb * 64;
#pragma unroll
        for (int i = 0; i < 4; ++i) gload16(sK + i * 32, dK + i * 2048);
#pragma unroll
        for (int i = 0; i < 4; ++i) gload16(sV + i * 16, dV + i * 2048);
    };

    f32x4 oaccA[8] = {}, oaccB[8] = {};
    float mA = -1e30f, lA = 0.f, mB = -1e30f, lB = 0.f;

    auto process = [&](const s16x8* aq, f32x4* oacc, float& mr, float& lr, int qrow0,
                       char* pw, const unsigned short* ks, const unsigned short* vs, int kb) {
        f32x4 s[4] = {};
#pragma unroll
        for (int kc = 0; kc < 4; ++kc)
#pragma unroll
            for (int kt = 0; kt < 4; ++kt) {
                s16x8 kf = *(const s16x8*)(ks + ((kc * 4 + g) * 64 + kt * 16 + l15) * 8);
                s[kt] = __builtin_amdgcn_mfma_f32_16x16x32_bf16(kf, aq[kc], s[kt], 0, 0, 0);
            }
        const int q = qrow0 + l15;
        if (kb * 64 + 63 > qrow0) {
#pragma unroll
            for (int kt = 0; kt < 4; ++kt)
#pragma unroll
                for (int r = 0; r < 4; ++r) {
                    float xv = s[kt][r] * SCALE_F;
                    s[kt][r] = (kb * 64 + kt * 16 + g * 4 + r > q) ? -3e38f : xv;
                }
        } else {
#pragma unroll
            for (int kt = 0; kt < 4; ++kt)
#pragma unroll
                for (int r = 0; r < 4; ++r) s[kt][r] *= SCALE_F;
        }
        float mx = -3e38f;
#pragma unroll
        for (int kt = 0; kt < 4; ++kt)
#pragma unroll
            for (int r = 0; r < 4; ++r) mx = fmaxf(mx, s[kt][r]);
        mx = fmaxf(mx, __shfl_xor(mx, 16));
        mx = fmaxf(mx, __shfl_xor(mx, 32));
        const float mnew = fmaxf(mr, mx);
        const float scal = __expf(mr - mnew);
        mr = mnew;
        float ps = 0.f;
#pragma unroll
        for (int kt = 0; kt < 4; ++kt)
#pragma unroll
            for (int r = 0; r < 4; ++r) {
                float p = __expf(s[kt][r] - mnew);
                s[kt][r] = p;
                ps += p;
            }
        ps += __shfl_xor(ps, 16);
        ps += __shfl_xor(ps, 32);
        lr = lr * scal + ps;
        float so[4];
#pragma unroll
        for (int r = 0; r < 4; ++r) so[r] = __shfl(scal, g * 4 + r, 16);
#pragma unroll
        for (int j = 0; j < 8; ++j) {
            oacc[j][0] *= so[0]; oacc[j][1] *= so[1];
            oacc[j][2] *= so[2]; oacc[j][3] *= so[3];
        }
#pragma unroll
        for (int kt = 0; kt < 4; ++kt) {
            unsigned int w0 = (unsigned int)f32_to_bf16(s[kt][0]) | ((unsigned int)f32_to_bf16(s[kt][1]) << 16);
            unsigned int w1 = (unsigned int)f32_to_bf16(s[kt][2]) | ((unsigned int)f32_to_bf16(s[kt][3]) << 16);
            const int b0 = (l15 * 128 + kt * 32 + g * 8) ^ swz;
            *(unsigned int*)(pw + b0) = w0;
            *(unsigned int*)(pw + b0 + 4) = w1;
        }
#pragma unroll
        for (int kc = 0; kc < 2; ++kc) {
            s16x8 pa = *(const s16x8*)(pw + ((l15 * 128 + kc * 64 + g * 16) ^ swz));
#pragma unroll
            for (int j = 0; j < 8; ++j) {
                s16x8 bv = *(const s16x8*)(vs + ((kc * 4 + g) * 128 + j * 16 + l15) * 8);
                oacc[j] = __builtin_amdgcn_mfma_f32_16x16x32_bf16(pa, bv, oacc[j], 0, 0, 0);
            }
        }
    };

    const int nkb = qbB + 1;
    stage(0);
    for (int kb = 0; kb < nkb; ++kb) {
        if (kb + 1 < nkb) {
            stage(kb + 1);
            asm volatile("s_waitcnt vmcnt(8)" ::: "memory");
        } else {
            asm volatile("s_waitcnt vmcnt(0)" ::: "memory");
        }
        __builtin_amdgcn_s_barrier();
        const unsigned short* ks = Ks[kb & 1];
        const unsigned short* vs = Vs[kb & 1];
        process(aqB, oaccB, mB, lB, qrB, (char*)Pl[1][wid], ks, vs, kb);
        if (kb <= qbA)
            process(aqA, oaccA, mA, lA, qrA, (char*)Pl[0][wid], ks, vs, kb);
        __builtin_amdgcn_s_barrier();
    }
    float liA[4], liB[4];
#pragma unroll
    for (int r = 0; r < 4; ++r) {
        liA[r] = 1.f / __shfl(lA, g * 4 + r, 16);
        liB[r] = 1.f / __shfl(lB, g * 4 + r, 16);
    }
#pragma unroll
    for (int j = 0; j < 8; ++j)
#pragma unroll
        for (int r = 0; r < 4; ++r) {
            Ob[(size_t)(qrA + g * 4 + r) * 4096 + h * 128 + j * 16 + l15] = f32_to_bf16(oaccA[j][r] * liA[r]);
            Ob[(size_t)(qrB + g * 4 + r) * 4096 + h * 128 + j * 16 + l15] = f32_to_bf16(oaccB[j][r] * liB[r]);
        }
}

extern "C" void kernel_launch(void* const* d_in, const int* in_sizes, int n_in,
                              void* d_out, int out_size, void* d_ws, size_t ws_size,
                              hipStream_t stream) {
    const float* x     = (const float*)d_in[0];
    const float* cosT  = (const float*)d_in[2];
    const float* sinT  = (const float*)d_in[3];
    const float* w_qkv = (const float*)d_in[4];
    const float* w_o   = (const float*)d_in[5];
    float* out = (float*)d_out;

    char* ws = (char*)d_ws;
    unsigned short* wT  = (unsigned short*)(ws + 0);
    float*          qkv = (float*)(ws + 50331648);
    unsigned short* Ob  = (unsigned short*)(ws + 50331648);
    unsigned short* xb  = (unsigned short*)(ws + 100663296);
    unsigned short* Qb  = xb;
    unsigned short* Kb  = (unsigned short*)(ws + 117440512);
    unsigned short* Vt  = (unsigned short*)(ws + 121634816);

    k_conv_bf16<<<8192, 256, 0, stream>>>(x, xb, 2097152);
    k_transpose_bf16<<<dim3(96, 64), 256, 0, stream>>>(w_qkv, wT, 4096, 6144, 0);
    k_gemm8p<256><<<192, 512, 0, stream>>>(xb, wT, qkv, 6144, 4096);
    k_rope_pack<<<dim3(20, 2048), 256, 0, stream>>>(qkv, cosT, sinT, Qb, Kb);
    k_transpose_bf16<<<dim3(16, 32), 256, 0, stream>>>(qkv, Vt, 2048, 6144, 5120);   // V^T
    k_transpose_bf16<<<dim3(64, 64), 256, 0, stream>>>(w_o, wT, 4096, 4096, 0);
    k_attn<<<dim3(16, 32), 256, 0, stream>>>(Qb, Kb, Vt, Ob);
    k_gemm8p<128><<<256, 512, 0, stream>>>(Ob, wT, out, 4096, 4096);
}